// Round 3
// baseline (322.373 us; speedup 1.0000x reference)
//
#include <hip/hip_runtime.h>

// sample_pdf (NeRF hierarchical sampling), fp32.
// bins: [N, 64] sorted edges; weights: [N, 63]; u: [N, 128] -> out [N, 128].
//
// R1: LDS-pipe bound. R2: DPP scan + 3 reg levels (325 us).
// R3: bpermute gathers + flat level-A + rcp. VALU 57->41%, dur flat -> latency.
// R4: 2 rays/wave ILP: 123->107 us, but VGPR stayed 16 -> compiler SERIALIZED
//     the 6 "independent" loads (can't hold results+addrs in 16 regs).
//     Waves stall ~2/3 of lifetime on exposed HBM latency; HBM only 31%.
// R5 (this): persistent waves (2048 blocks, chip-resident) + software-pipelined
//     register double-buffer: issue next pair's 6 loads BEFORE computing the
//     current pair (loads land in a separate named RayBuf; no arithmetic on
//     them until next iteration). Forces the allocator to keep both buffers
//     live -> loads genuinely overlap compute. Target: HBM-/VALU-bound.

constexpr int NBINS = 64;
constexpr int NW = NBINS - 1;
constexpr int NIMP = 128;
constexpr int WAVES_PER_BLOCK = 4;
constexpr int MAX_BLOCKS = 2048;   // 8 blocks/CU x 256 CU: exactly resident

template <int Ctrl, int Rm>
__device__ __forceinline__ float dppterm(float x) {
    // update_dpp(old=0,...): lanes with invalid source (bound_ctrl) or masked-off
    // rows (row_mask) produce 0, so "x += dppterm(x)" is the identity there.
    return __int_as_float(__builtin_amdgcn_update_dpp(
        0, __float_as_int(x), Ctrl, Rm, 0xF, true));
}

__device__ __forceinline__ float rdlane(float x, int lane) {
    return __int_as_float(__builtin_amdgcn_readlane(__float_as_int(x), lane));
}

// pull: result = src@lane[idx] (full wave64 crossbar on register values)
__device__ __forceinline__ float bperm_f(float x, int lane_idx) {
    return __int_as_float(
        __builtin_amdgcn_ds_bpermute(lane_idx << 2, __float_as_int(x)));
}

// wave64 inclusive scan, pure VALU (DPP), no DS ops
__device__ __forceinline__ float wave_incl_scan(float x) {
    x += dppterm<0x111, 0xF>(x);  // row_shr:1
    x += dppterm<0x112, 0xF>(x);  // row_shr:2
    x += dppterm<0x114, 0xF>(x);  // row_shr:4
    x += dppterm<0x118, 0xF>(x);  // row_shr:8  -> per-16 row scans
    x += dppterm<0x142, 0xA>(x);  // row_bcast:15 -> rows 1,3 get row 0/2 totals
    x += dppterm<0x143, 0xC>(x);  // row_bcast:31 -> lanes 32..63 get total(0..31)
    return x;
}

struct Pivots { float c8, c16, c24, c32, c40, c48, c56; };

__device__ __forceinline__ Pivots make_pivots(float cdfv) {
    Pivots p;
    p.c8  = rdlane(cdfv, 8);
    p.c16 = rdlane(cdfv, 16);
    p.c24 = rdlane(cdfv, 24);
    p.c32 = rdlane(cdfv, 32);
    p.c40 = rdlane(cdfv, 40);
    p.c48 = rdlane(cdfv, 48);
    p.c56 = rdlane(cdfv, 56);
    return p;
}

__device__ __forceinline__ float sample_one(float uv, const float* cdf,
                                            float cdfv, float bv,
                                            const Pivots& P)
{
    // level A: which 8-aligned group (pivots sorted => flags monotone => sum)
    const int grp = (int)(P.c8 < uv) + (int)(P.c16 < uv) + (int)(P.c24 < uv) +
                    (int)(P.c32 < uv) + (int)(P.c40 < uv) + (int)(P.c48 < uv) +
                    (int)(P.c56 < uv);
    const int pos = grp << 3;  // 32B-aligned LDS offset

    // level B: 8-entry range in one lgkm round (2 independent b128)
    const float4 g0 = *(const float4*)(cdf + pos);
    const float4 g1 = *(const float4*)(cdf + pos + 4);
    const int cnt = (int)(g0.y < uv) + (int)(g0.z < uv) + (int)(g0.w < uv) +
                    (int)(g1.x < uv) + (int)(g1.y < uv) + (int)(g1.z < uv) +
                    (int)(g1.w < uv);

    // lower = largest i with cdf[i] < uv (0 if none); cdf[63]=1 exact keeps
    // lower<=62 for uv<1. uv<=0 -> upper=0 -> chi=cdf[0]=0 falls out free.
    const int lower = pos + cnt;
    const int upper = (uv > 0.0f) ? (lower + 1) : 0;

    // all 4 gathers in one parallel crossbar round
    const float lo  = bperm_f(cdfv, lower);
    const float chi = bperm_f(cdfv, upper);
    const float blo = bperm_f(bv, lower);
    const float bhi = bperm_f(bv, upper);

    float denom = chi - lo;
    denom = (denom < 1e-5f) ? 1.0f : denom;
    const float t = (uv - lo) * __builtin_amdgcn_rcpf(denom);
    return __builtin_fmaf(t, bhi - blo, blo);
}

// Per-ray load payload. issue_loads does NO arithmetic on the loaded values,
// so the compiler can leave them in flight until the next iteration's compute.
struct RayBuf { float bv, w; float2 uu; };

__device__ __forceinline__ RayBuf issue_loads(
    const float* __restrict__ bins, const float* __restrict__ weights,
    const float* __restrict__ u, uint32_t r, int lane)
{
    RayBuf b;
    b.bv = bins[r * NBINS + lane];
    b.w = 0.0f;
    if (lane < NW) b.w = weights[r * NW + lane];   // exec-masked load, no math
    b.uu = ((const float2*)u)[r * (NIMP / 2) + lane];
    return b;
}

__global__ __launch_bounds__(256) void sample_pdf_kernel(
    const float* __restrict__ bins,
    const float* __restrict__ weights,
    const float* __restrict__ u,
    float* __restrict__ out,
    int n_rays)
{
    __shared__ alignas(16) float s_cdf[WAVES_PER_BLOCK][2][NBINS];

    const int wave = threadIdx.x >> 6;
    const int lane = threadIdx.x & 63;
    const int gwave  = blockIdx.x * WAVES_PER_BLOCK + wave;
    const int nwaves = gridDim.x * WAVES_PER_BLOCK;
    const int npairs = (n_rays + 1) >> 1;     // ray-pairs (rays 2p, 2p+1)

    float* cA = s_cdf[wave][0];
    float* cB = s_cdf[wave][1];

    // prologue: issue first pair's loads (clamped indices are always valid)
    int p = gwave;
    {
        const int pc = min(p, npairs - 1);
        const uint32_t rA = (uint32_t)min(2 * pc,     n_rays - 1);
        const uint32_t rB = (uint32_t)min(2 * pc + 1, n_rays - 1);
        RayBuf a0 = issue_loads(bins, weights, u, rA, lane);
        RayBuf a1 = issue_loads(bins, weights, u, rB, lane);

        while (p < npairs) {
            // ---- issue NEXT pair's loads first (overlap with compute below) ----
            const int pn = p + nwaves;
            const int pc2 = min(pn, npairs - 1);           // dead-prefetch on last iter
            const uint32_t rA2 = (uint32_t)min(2 * pc2,     n_rays - 1);
            const uint32_t rB2 = (uint32_t)min(2 * pc2 + 1, n_rays - 1);
            RayBuf b0 = issue_loads(bins, weights, u, rA2, lane);
            RayBuf b1 = issue_loads(bins, weights, u, rB2, lane);

            // ---- compute current pair ----
            const uint32_t r0 = (uint32_t)min(2 * p,     n_rays - 1);
            const uint32_t r1 = (uint32_t)min(2 * p + 1, n_rays - 1);

            const float wA = (lane < NW) ? (a0.w + 1e-5f) : 0.0f;
            const float wB = (lane < NW) ? (a1.w + 1e-5f) : 0.0f;
            const float SA = wave_incl_scan(wA);
            const float SB = wave_incl_scan(wB);
            float cdfvA = (SA - wA) * __builtin_amdgcn_rcpf(rdlane(SA, 63));
            float cdfvB = (SB - wB) * __builtin_amdgcn_rcpf(rdlane(SB, 63));
            if (lane == NBINS - 1) { cdfvA = 1.0f; cdfvB = 1.0f; }  // exact top

            // wave-private LDS rows; same-wave write->read order via lgkmcnt
            cA[lane] = cdfvA;
            cB[lane] = cdfvB;

            const Pivots PA = make_pivots(cdfvA);
            const Pivots PB = make_pivots(cdfvB);

            float2 resA, resB;
            resA.x = sample_one(a0.uu.x, cA, cdfvA, a0.bv, PA);
            resA.y = sample_one(a0.uu.y, cA, cdfvA, a0.bv, PA);
            resB.x = sample_one(a1.uu.x, cB, cdfvB, a1.bv, PB);
            resB.y = sample_one(a1.uu.y, cB, cdfvB, a1.bv, PB);

            ((float2*)out)[r0 * (NIMP / 2) + lane] = resA;
            ((float2*)out)[r1 * (NIMP / 2) + lane] = resB;

            // rotate buffers
            a0 = b0;
            a1 = b1;
            p = pn;
        }
    }
}

extern "C" void kernel_launch(void* const* d_in, const int* in_sizes, int n_in,
                              void* d_out, int out_size, void* d_ws, size_t ws_size,
                              hipStream_t stream) {
    const float* bins    = (const float*)d_in[0];
    const float* weights = (const float*)d_in[1];
    const float* u       = (const float*)d_in[2];
    float* out = (float*)d_out;

    const int n_rays = in_sizes[0] / NBINS;
    const int npairs = (n_rays + 1) / 2;
    int blocks = (npairs + WAVES_PER_BLOCK - 1) / WAVES_PER_BLOCK;
    if (blocks > MAX_BLOCKS) blocks = MAX_BLOCKS;
    sample_pdf_kernel<<<blocks, 256, 0, stream>>>(bins, weights, u, out, n_rays);
}

// Round 4
// 305.523 us; speedup vs baseline: 1.0552x; 1.0552x over previous
//
#include <hip/hip_runtime.h>

// sample_pdf (NeRF hierarchical sampling), fp32.
// bins: [N, 64] sorted edges; weights: [N, 63]; u: [N, 128] -> out [N, 128].
//
// R1: LDS-pipe bound. R2: DPP scan + 3 reg levels (325 us).
// R3: bpermute gathers + flat level-A + rcp. VALU 57->41%, dur flat -> latency.
// R4: 2 rays/wave ILP: 107 us. BUT VGPR_Count=16 -> compiler SERIALIZED the 6
//     loads (can't hold 8 result + 12 addr regs in 16): wave lifetime ~13K cyc
//     = 6 HBM round-trips. Latency-bound, no pipe >50%.
// R5: persistent waves + SW pipeline: REGRESSED (VGPR 24, pipeline collapsed,
//     occupancy 66%). Reverted.
// R6 (this): R4 structure + asm keep-alive marker reading ALL load results
//     before first use. Forces simultaneous liveness -> allocator can't reuse
//     load dest regs -> no intermediate waitcnts -> 6 loads in flight, ONE
//     vmcnt(0) drain, one round-trip. Expect VGPR ~32, wave lifetime ~3K cyc,
//     VALU pipe -> saturation.

constexpr int NBINS = 64;
constexpr int NW = NBINS - 1;
constexpr int NIMP = 128;
constexpr int WAVES_PER_BLOCK = 4;
constexpr int RAYS_PER_WAVE = 2;
constexpr int RAYS_PER_BLOCK = WAVES_PER_BLOCK * RAYS_PER_WAVE;  // 8

template <int Ctrl, int Rm>
__device__ __forceinline__ float dppterm(float x) {
    // update_dpp(old=0,...): lanes with invalid source (bound_ctrl) or masked-off
    // rows (row_mask) produce 0, so "x += dppterm(x)" is the identity there.
    return __int_as_float(__builtin_amdgcn_update_dpp(
        0, __float_as_int(x), Ctrl, Rm, 0xF, true));
}

__device__ __forceinline__ float rdlane(float x, int lane) {
    return __int_as_float(__builtin_amdgcn_readlane(__float_as_int(x), lane));
}

// pull: result = src@lane[idx] (full wave64 crossbar on register values)
__device__ __forceinline__ float bperm_f(float x, int lane_idx) {
    return __int_as_float(
        __builtin_amdgcn_ds_bpermute(lane_idx << 2, __float_as_int(x)));
}

// wave64 inclusive scan, pure VALU (DPP), no DS ops
__device__ __forceinline__ float wave_incl_scan(float x) {
    x += dppterm<0x111, 0xF>(x);  // row_shr:1
    x += dppterm<0x112, 0xF>(x);  // row_shr:2
    x += dppterm<0x114, 0xF>(x);  // row_shr:4
    x += dppterm<0x118, 0xF>(x);  // row_shr:8  -> per-16 row scans
    x += dppterm<0x142, 0xA>(x);  // row_bcast:15 -> rows 1,3 get row 0/2 totals
    x += dppterm<0x143, 0xC>(x);  // row_bcast:31 -> lanes 32..63 get total(0..31)
    return x;
}

struct Pivots { float c8, c16, c24, c32, c40, c48, c56; };

__device__ __forceinline__ Pivots make_pivots(float cdfv) {
    Pivots p;
    p.c8  = rdlane(cdfv, 8);
    p.c16 = rdlane(cdfv, 16);
    p.c24 = rdlane(cdfv, 24);
    p.c32 = rdlane(cdfv, 32);
    p.c40 = rdlane(cdfv, 40);
    p.c48 = rdlane(cdfv, 48);
    p.c56 = rdlane(cdfv, 56);
    return p;
}

__device__ __forceinline__ float sample_one(float uv, const float* cdf,
                                            float cdfv, float bv,
                                            const Pivots& P)
{
    // level A: which 8-aligned group (pivots sorted => flags monotone => sum)
    const int grp = (int)(P.c8 < uv) + (int)(P.c16 < uv) + (int)(P.c24 < uv) +
                    (int)(P.c32 < uv) + (int)(P.c40 < uv) + (int)(P.c48 < uv) +
                    (int)(P.c56 < uv);
    const int pos = grp << 3;  // 32B-aligned LDS offset

    // level B: 8-entry range in one lgkm round (2 independent b128)
    const float4 g0 = *(const float4*)(cdf + pos);
    const float4 g1 = *(const float4*)(cdf + pos + 4);
    const int cnt = (int)(g0.y < uv) + (int)(g0.z < uv) + (int)(g0.w < uv) +
                    (int)(g1.x < uv) + (int)(g1.y < uv) + (int)(g1.z < uv) +
                    (int)(g1.w < uv);

    // lower = largest i with cdf[i] < uv (0 if none); cdf[63]=1 exact keeps
    // lower<=62 for uv<1. uv<=0 -> upper=0 -> chi=cdf[0]=0 falls out free.
    const int lower = pos + cnt;
    const int upper = (uv > 0.0f) ? (lower + 1) : 0;

    // all 4 gathers in one parallel crossbar round
    const float lo  = bperm_f(cdfv, lower);
    const float chi = bperm_f(cdfv, upper);
    const float blo = bperm_f(bv, lower);
    const float bhi = bperm_f(bv, upper);

    float denom = chi - lo;
    denom = (denom < 1e-5f) ? 1.0f : denom;
    const float t = (uv - lo) * __builtin_amdgcn_rcpf(denom);
    return __builtin_fmaf(t, bhi - blo, blo);
}

__global__ __launch_bounds__(256) void sample_pdf_kernel(
    const float* __restrict__ bins,
    const float* __restrict__ weights,
    const float* __restrict__ u,
    float* __restrict__ out,
    int n_rays)
{
    __shared__ alignas(16) float s_cdf[WAVES_PER_BLOCK][RAYS_PER_WAVE][NBINS];

    const int wave = threadIdx.x >> 6;
    const int lane = threadIdx.x & 63;
    const int base = blockIdx.x * RAYS_PER_BLOCK + wave * RAYS_PER_WAVE;
    // tail: clamped rays recompute ray n-1; identical values, benign dup writes
    const uint32_t rA = (uint32_t)min(base,     n_rays - 1);
    const uint32_t rB = (uint32_t)min(base + 1, n_rays - 1);

    // ---- issue all 6 global loads; results in 8 distinct named regs ----
    const float bvA = bins[rA * NBINS + lane];
    const float bvB = bins[rB * NBINS + lane];
    float wrA = 0.0f, wrB = 0.0f;
    if (lane < NW) {
        wrA = weights[rA * NW + lane];   // exec-masked loads, no math on results
        wrB = weights[rB * NW + lane];
    }
    const float2 uuA = ((const float2*)u)[rA * (NIMP / 2) + lane];
    const float2 uuB = ((const float2*)u)[rB * (NIMP / 2) + lane];

    // Keep-alive marker: forces all 8 load results simultaneously live BEFORE
    // any consumption. Allocator cannot reuse dest regs -> waitcnt pass emits
    // no intermediate waits -> all 6 loads overlap in flight; single vmcnt
    // drain here. This is the whole point of R6 (R4 serialized at VGPR=16).
    asm volatile("" :: "v"(bvA), "v"(bvB), "v"(wrA), "v"(wrB),
                       "v"(uuA.x), "v"(uuA.y), "v"(uuB.x), "v"(uuB.y));

    // weights + 1e-5 -> two independent DPP scans -> exclusive normalized cdfs
    const float wA = (lane < NW) ? (wrA + 1e-5f) : 0.0f;
    const float wB = (lane < NW) ? (wrB + 1e-5f) : 0.0f;
    const float SA = wave_incl_scan(wA);
    const float SB = wave_incl_scan(wB);
    float cdfvA = (SA - wA) * __builtin_amdgcn_rcpf(rdlane(SA, 63));
    float cdfvB = (SB - wB) * __builtin_amdgcn_rcpf(rdlane(SB, 63));
    if (lane == NBINS - 1) { cdfvA = 1.0f; cdfvB = 1.0f; }  // exact top

    // wave-private LDS rows; same-wave write->read order via compiler lgkmcnt
    s_cdf[wave][0][lane] = cdfvA;
    s_cdf[wave][1][lane] = cdfvB;

    const Pivots PA = make_pivots(cdfvA);
    const Pivots PB = make_pivots(cdfvB);

    const float* cA = s_cdf[wave][0];
    const float* cB = s_cdf[wave][1];

    // 4 independent sample chains
    float2 resA, resB;
    resA.x = sample_one(uuA.x, cA, cdfvA, bvA, PA);
    resA.y = sample_one(uuA.y, cA, cdfvA, bvA, PA);
    resB.x = sample_one(uuB.x, cB, cdfvB, bvB, PB);
    resB.y = sample_one(uuB.y, cB, cdfvB, bvB, PB);

    ((float2*)out)[rA * (NIMP / 2) + lane] = resA;
    ((float2*)out)[rB * (NIMP / 2) + lane] = resB;
}

extern "C" void kernel_launch(void* const* d_in, const int* in_sizes, int n_in,
                              void* d_out, int out_size, void* d_ws, size_t ws_size,
                              hipStream_t stream) {
    const float* bins    = (const float*)d_in[0];
    const float* weights = (const float*)d_in[1];
    const float* u       = (const float*)d_in[2];
    float* out = (float*)d_out;

    const int n_rays = in_sizes[0] / NBINS;
    const int grid = (n_rays + RAYS_PER_BLOCK - 1) / RAYS_PER_BLOCK;
    sample_pdf_kernel<<<grid, 256, 0, stream>>>(bins, weights, u, out, n_rays);
}